// Round 1
// baseline (93.672 us; speedup 1.0000x reference)
//
#include <hip/hip_runtime.h>
#include <hip/hip_bf16.h>

#define NN 4096
#define DD 512
#define BM 128
#define BK 32
#define LDP 40   // padded LDS row stride in bf16 elements (128B->80B rows, conflict-free)
#define TILES 32                    // NN/BM
#define TRI   (TILES*(TILES+1)/2)   // 528

typedef __attribute__((ext_vector_type(8))) short short8v;
typedef __attribute__((ext_vector_type(4))) short short4v;
typedef __attribute__((ext_vector_type(4))) float f32x4;

// fp32 -> bf16 RNE via integer rounding (3 VALU ops, no lib dependence)
static __device__ __forceinline__ short f2bf(float f) {
    union { float f; unsigned u; } a; a.f = f;
    unsigned r = a.u + 0x7FFFu + ((a.u >> 16) & 1u);
    return (short)(r >> 16);
}

// Row squared-norms for x and y. One wave per row, 8192 rows total.
__global__ void norms_kernel(const float* __restrict__ x, const float* __restrict__ y,
                             float* __restrict__ nx, float* __restrict__ ny) {
    int wid  = (blockIdx.x * blockDim.x + threadIdx.x) >> 6;   // 0..8191
    int lane = threadIdx.x & 63;
    const float* src = (wid < NN) ? x : y;
    int row = wid & (NN - 1);
    const float4* p = (const float4*)(src + (size_t)row * DD);
    float s = 0.f;
    #pragma unroll
    for (int i = 0; i < 2; ++i) {
        float4 v = p[lane + 64 * i];
        s += v.x * v.x + v.y * v.y + v.z * v.z + v.w * v.w;
    }
    #pragma unroll
    for (int off = 32; off > 0; off >>= 1) s += __shfl_down(s, off);
    if (lane == 0) ((wid < NN) ? nx : ny)[row] = s;
}

// Fused Gram-tile + epilogue reduction.
// p=0: X·X^T (triangular, weight 2 off-diag)  -> + mean(exp(-d2xx))
// p=1: Y·Y^T (triangular)                      -> + mean(exp(-d2yy))
// p=2: X·Y^T (full)                            -> + mean((g-I)^2) - 2*mean(exp(-d2xy))
__global__ void __launch_bounds__(256)
fused_kernel(const float* __restrict__ x, const float* __restrict__ y,
             const float* __restrict__ nx, const float* __restrict__ ny,
             float* __restrict__ out) {
    __shared__ __align__(16) short As[BM * LDP];
    __shared__ __align__(16) short Bs[BM * LDP];
    __shared__ float wsum[4];

    int bid = blockIdx.x;
    int p, ti, tj; float w = 1.f;
    if (bid < TILES * TILES) {
        p = 2; ti = bid >> 5; tj = bid & (TILES - 1);
    } else {
        int u = bid - TILES * TILES;
        p = 0;
        if (u >= TRI) { p = 1; u -= TRI; }
        int a = 0;
        while (u >= TILES - a) { u -= TILES - a; ++a; }
        ti = a; tj = a + u;
        if (ti != tj) w = 2.f;
    }
    const float* P  = (p == 1) ? y  : x;
    const float* Q  = (p == 0) ? x  : y;
    const float* NA = (p == 1) ? ny : nx;
    const float* NB = (p == 0) ? nx : ny;

    const int t    = threadIdx.x;
    const int lane = t & 63;
    const int wvid = t >> 6;
    const int wm = wvid >> 1, wn = wvid & 1;

    f32x4 acc[4][4];
    #pragma unroll
    for (int m = 0; m < 4; ++m)
        #pragma unroll
        for (int n = 0; n < 4; ++n)
            acc[m][n] = (f32x4){0.f, 0.f, 0.f, 0.f};

    const int srow = t >> 3;        // 0..31
    const int scol = (t & 7) * 4;   // 0..28 (float index within BK)
    const size_t baseA = (size_t)(ti * BM) * DD;
    const size_t baseB = (size_t)(tj * BM) * DD;

    for (int kt = 0; kt < DD; kt += BK) {
        #pragma unroll
        for (int s = 0; s < 4; ++s) {
            int r = s * 32 + srow;
            float4 va = *(const float4*)(P + baseA + (size_t)r * DD + kt + scol);
            float4 vb = *(const float4*)(Q + baseB + (size_t)r * DD + kt + scol);
            short4v ha = { f2bf(va.x), f2bf(va.y), f2bf(va.z), f2bf(va.w) };
            short4v hb = { f2bf(vb.x), f2bf(vb.y), f2bf(vb.z), f2bf(vb.w) };
            *(short4v*)(&As[r * LDP + scol]) = ha;
            *(short4v*)(&Bs[r * LDP + scol]) = hb;
        }
        __syncthreads();

        short8v af[4], bfr[4];
        const int kc = (lane >> 4) * 8;
        #pragma unroll
        for (int m = 0; m < 4; ++m)
            af[m] = *(const short8v*)(&As[(wm * 64 + m * 16 + (lane & 15)) * LDP + kc]);
        #pragma unroll
        for (int n = 0; n < 4; ++n)
            bfr[n] = *(const short8v*)(&Bs[(wn * 64 + n * 16 + (lane & 15)) * LDP + kc]);
        #pragma unroll
        for (int m = 0; m < 4; ++m)
            #pragma unroll
            for (int n = 0; n < 4; ++n)
                acc[m][n] = __builtin_amdgcn_mfma_f32_16x16x32_bf16(af[m], bfr[n], acc[m][n], 0, 0, 0);
        __syncthreads();
    }

    // Epilogue: per-element terms, thread-local sum.
    float local = 0.f;
    #pragma unroll
    for (int m = 0; m < 4; ++m) {
        #pragma unroll
        for (int n = 0; n < 4; ++n) {
            #pragma unroll
            for (int r = 0; r < 4; ++r) {
                int row = wm * 64 + m * 16 + ((lane >> 4) << 2) + r;
                int col = wn * 64 + n * 16 + (lane & 15);
                int gr = ti * BM + row, gc = tj * BM + col;
                float g  = acc[m][n][r];
                float d2 = fmaxf(NA[gr] + NB[gc] - 2.f * g, 0.f);
                float e  = __expf(-d2);
                if (p == 2) {
                    float diff = g - ((gr == gc) ? 1.f : 0.f);
                    local += diff * diff - 2.f * e;
                } else {
                    local += w * e;
                }
            }
        }
    }
    #pragma unroll
    for (int off = 32; off > 0; off >>= 1) local += __shfl_down(local, off);
    if (lane == 0) wsum[wvid] = local;
    __syncthreads();
    if (t == 0) {
        float s = (wsum[0] + wsum[1]) + (wsum[2] + wsum[3]);
        atomicAdd(out, s * (1.f / ((float)NN * (float)NN)));
    }
}

extern "C" void kernel_launch(void* const* d_in, const int* in_sizes, int n_in,
                              void* d_out, int out_size, void* d_ws, size_t ws_size,
                              hipStream_t stream) {
    const float* x = (const float*)d_in[0];
    const float* y = (const float*)d_in[1];
    float* out = (float*)d_out;
    float* nx = (float*)d_ws;       // 4096 floats
    float* ny = nx + NN;            // 4096 floats (32 KB total ws use)

    hipMemsetAsync(d_out, 0, sizeof(float), stream);
    norms_kernel<<<dim3(2048), dim3(256), 0, stream>>>(x, y, nx, ny);
    const int nblk = TILES * TILES + 2 * TRI;   // 1024 + 1056 = 2080
    fused_kernel<<<dim3(nblk), dim3(256), 0, stream>>>(x, y, nx, ny, out);
}

// Round 2
// 74.908 us; speedup vs baseline: 1.2505x; 1.2505x over previous
//
#include <hip/hip_runtime.h>
#include <hip/hip_bf16.h>

#define NN 4096
#define DD 512
#define BM 128
#define BK 32    // bf16 elements per K-step
#define LDP 40   // padded stride for fallback path only
#define TILES 32                    // NN/BM
#define TRI   (TILES*(TILES+1)/2)   // 528

typedef __attribute__((ext_vector_type(8))) short short8v;
typedef __attribute__((ext_vector_type(4))) short short4v;
typedef __attribute__((ext_vector_type(4))) float f32x4;

// fp32 -> bf16 RNE via integer rounding
static __device__ __forceinline__ short f2bf(float f) {
    union { float f; unsigned u; } a; a.f = f;
    unsigned r = a.u + 0x7FFFu + ((a.u >> 16) & 1u);
    return (short)(r >> 16);
}

static __device__ __forceinline__ void stage16(const void* g, void* l) {
    __builtin_amdgcn_global_load_lds(
        (const __attribute__((address_space(1))) unsigned int*)g,
        (__attribute__((address_space(3))) unsigned int*)l, 16, 0, 0);
}

// Decode blockIdx -> (pass, tile_i, tile_j, weight)
static __device__ __forceinline__ void decode_tile(int bid, int& p, int& ti, int& tj, float& w) {
    w = 1.f;
    if (bid < TILES * TILES) {
        p = 2; ti = bid >> 5; tj = bid & (TILES - 1);
    } else {
        int u = bid - TILES * TILES;
        p = 0;
        if (u >= TRI) { p = 1; u -= TRI; }
        int a = 0;
        while (u >= TILES - a) { u -= TILES - a; ++a; }
        ti = a; tj = a + u;
        if (ti != tj) w = 2.f;
    }
}

// ---------- fast path ----------

// Convert fp32 rows -> bf16 workspace AND compute row squared-norms.
// One wave per row, 8192 rows.
__global__ void prep_kernel(const float* __restrict__ x, const float* __restrict__ y,
                            ushort* __restrict__ bx, ushort* __restrict__ by,
                            float* __restrict__ nx, float* __restrict__ ny) {
    int wid  = (blockIdx.x * blockDim.x + threadIdx.x) >> 6;   // 0..8191
    int lane = threadIdx.x & 63;
    bool isx = wid < NN;
    const float* src = isx ? x : y;
    ushort* dst = isx ? bx : by;
    int row = wid & (NN - 1);
    const float4* p = (const float4*)(src + (size_t)row * DD);
    float s = 0.f;
    #pragma unroll
    for (int i = 0; i < 2; ++i) {
        float4 v = p[lane + 64 * i];
        s += v.x * v.x + v.y * v.y + v.z * v.z + v.w * v.w;
        short4v h = { f2bf(v.x), f2bf(v.y), f2bf(v.z), f2bf(v.w) };
        *(short4v*)(dst + (size_t)row * DD + 4 * (lane + 64 * i)) = h;
    }
    #pragma unroll
    for (int off = 32; off > 0; off >>= 1) s += __shfl_down(s, off);
    if (lane == 0) (isx ? nx : ny)[row] = s;
}

// m97-structure fused Gram-tile + epilogue reduction, bf16 inputs,
// global_load_lds width-16 staging into linear LDS.
__global__ void __launch_bounds__(256)
fused2_kernel(const ushort* __restrict__ bx, const ushort* __restrict__ by,
              const float* __restrict__ nx, const float* __restrict__ ny,
              float* __restrict__ out) {
    __shared__ __align__(16) ushort As[BM * BK];
    __shared__ __align__(16) ushort Bs[BM * BK];
    __shared__ float wsum[4];

    int p, ti, tj; float w;
    decode_tile(blockIdx.x, p, ti, tj, w);

    const ushort* PB = (p == 1) ? by : bx;
    const ushort* QB = (p == 0) ? bx : by;
    const float*  NA = (p == 1) ? ny : nx;
    const float*  NB = (p == 0) ? nx : ny;

    const int t    = threadIdx.x;
    const int lane = t & 63;
    const int wvid = t >> 6;
    const int wm = wvid >> 1, wn = wvid & 1;

    f32x4 acc[4][4];
    #pragma unroll
    for (int m = 0; m < 4; ++m)
        #pragma unroll
        for (int n = 0; n < 4; ++n)
            acc[m][n] = (f32x4){0.f, 0.f, 0.f, 0.f};

    const size_t rowA0 = (size_t)ti * BM;
    const size_t rowB0 = (size_t)tj * BM;
    const int lrow = lane >> 2;          // 0..15 within 16-row segment
    const int lke  = (lane & 3) * 8;     // 0,8,16,24

    for (int kt = 0; kt < DD; kt += BK) {
        #pragma unroll
        for (int i = 0; i < 2; ++i) {
            int seg = wvid * 2 + i;                       // 0..7, wave-uniform
            int row = seg * 16 + lrow;
            const ushort* ga = PB + (rowA0 + row) * DD + kt + lke;
            const ushort* gb = QB + (rowB0 + row) * DD + kt + lke;
            stage16(ga, &As[seg * 16 * BK]);
            stage16(gb, &Bs[seg * 16 * BK]);
        }
        __syncthreads();   // drains vmcnt(0) for global_load_lds

        short8v af[4], bfr[4];
        const int kc = (lane >> 4) * 8;
        #pragma unroll
        for (int m = 0; m < 4; ++m)
            af[m] = *(const short8v*)(&As[(wm * 64 + m * 16 + (lane & 15)) * BK + kc]);
        #pragma unroll
        for (int n = 0; n < 4; ++n)
            bfr[n] = *(const short8v*)(&Bs[(wn * 64 + n * 16 + (lane & 15)) * BK + kc]);
        #pragma unroll
        for (int m = 0; m < 4; ++m)
            #pragma unroll
            for (int n = 0; n < 4; ++n)
                acc[m][n] = __builtin_amdgcn_mfma_f32_16x16x32_bf16(af[m], bfr[n], acc[m][n], 0, 0, 0);
        __syncthreads();
    }

    // Epilogue: hoist norms, then per-element terms.
    float nbv[4], nav[4][4];
    #pragma unroll
    for (int n = 0; n < 4; ++n)
        nbv[n] = NB[tj * BM + wn * 64 + n * 16 + (lane & 15)];
    #pragma unroll
    for (int m = 0; m < 4; ++m)
        #pragma unroll
        for (int r = 0; r < 4; ++r)
            nav[m][r] = NA[ti * BM + wm * 64 + m * 16 + ((lane >> 4) << 2) + r];

    float local = 0.f;
    #pragma unroll
    for (int m = 0; m < 4; ++m) {
        #pragma unroll
        for (int n = 0; n < 4; ++n) {
            #pragma unroll
            for (int r = 0; r < 4; ++r) {
                int row = wm * 64 + m * 16 + ((lane >> 4) << 2) + r;
                int col = wn * 64 + n * 16 + (lane & 15);
                int gr = ti * BM + row, gc = tj * BM + col;
                float g  = acc[m][n][r];
                float d2 = fmaxf(nav[m][r] + nbv[n] - 2.f * g, 0.f);
                float e  = __expf(-d2);
                if (p == 2) {
                    float diff = g - ((gr == gc) ? 1.f : 0.f);
                    local += diff * diff - 2.f * e;
                } else {
                    local += w * e;
                }
            }
        }
    }
    #pragma unroll
    for (int off = 32; off > 0; off >>= 1) local += __shfl_down(local, off);
    if (lane == 0) wsum[wvid] = local;
    __syncthreads();
    if (t == 0) {
        float s = (wsum[0] + wsum[1]) + (wsum[2] + wsum[3]);
        atomicAdd(out, s * (1.f / ((float)NN * (float)NN)));
    }
}

// ---------- fallback path (round-1 kernels, used only if ws too small) ----------

__global__ void norms_kernel(const float* __restrict__ x, const float* __restrict__ y,
                             float* __restrict__ nx, float* __restrict__ ny) {
    int wid  = (blockIdx.x * blockDim.x + threadIdx.x) >> 6;
    int lane = threadIdx.x & 63;
    const float* src = (wid < NN) ? x : y;
    int row = wid & (NN - 1);
    const float4* p = (const float4*)(src + (size_t)row * DD);
    float s = 0.f;
    #pragma unroll
    for (int i = 0; i < 2; ++i) {
        float4 v = p[lane + 64 * i];
        s += v.x * v.x + v.y * v.y + v.z * v.z + v.w * v.w;
    }
    #pragma unroll
    for (int off = 32; off > 0; off >>= 1) s += __shfl_down(s, off);
    if (lane == 0) ((wid < NN) ? nx : ny)[row] = s;
}

__global__ void __launch_bounds__(256)
fused_kernel(const float* __restrict__ x, const float* __restrict__ y,
             const float* __restrict__ nx, const float* __restrict__ ny,
             float* __restrict__ out) {
    __shared__ __align__(16) short As[BM * LDP];
    __shared__ __align__(16) short Bs[BM * LDP];
    __shared__ float wsum[4];

    int p, ti, tj; float w;
    decode_tile(blockIdx.x, p, ti, tj, w);
    const float* P  = (p == 1) ? y  : x;
    const float* Q  = (p == 0) ? x  : y;
    const float* NA = (p == 1) ? ny : nx;
    const float* NB = (p == 0) ? nx : ny;

    const int t    = threadIdx.x;
    const int lane = t & 63;
    const int wvid = t >> 6;
    const int wm = wvid >> 1, wn = wvid & 1;

    f32x4 acc[4][4];
    #pragma unroll
    for (int m = 0; m < 4; ++m)
        #pragma unroll
        for (int n = 0; n < 4; ++n)
            acc[m][n] = (f32x4){0.f, 0.f, 0.f, 0.f};

    const int srow = t >> 3;
    const int scol = (t & 7) * 4;
    const size_t baseA = (size_t)(ti * BM) * DD;
    const size_t baseB = (size_t)(tj * BM) * DD;

    for (int kt = 0; kt < DD; kt += BK) {
        #pragma unroll
        for (int s = 0; s < 4; ++s) {
            int r = s * 32 + srow;
            float4 va = *(const float4*)(P + baseA + (size_t)r * DD + kt + scol);
            float4 vb = *(const float4*)(Q + baseB + (size_t)r * DD + kt + scol);
            short4v ha = { f2bf(va.x), f2bf(va.y), f2bf(va.z), f2bf(va.w) };
            short4v hb = { f2bf(vb.x), f2bf(vb.y), f2bf(vb.z), f2bf(vb.w) };
            *(short4v*)(&As[r * LDP + scol]) = ha;
            *(short4v*)(&Bs[r * LDP + scol]) = hb;
        }
        __syncthreads();

        short8v af[4], bfr[4];
        const int kc = (lane >> 4) * 8;
        #pragma unroll
        for (int m = 0; m < 4; ++m)
            af[m] = *(const short8v*)(&As[(wm * 64 + m * 16 + (lane & 15)) * LDP + kc]);
        #pragma unroll
        for (int n = 0; n < 4; ++n)
            bfr[n] = *(const short8v*)(&Bs[(wn * 64 + n * 16 + (lane & 15)) * LDP + kc]);
        #pragma unroll
        for (int m = 0; m < 4; ++m)
            #pragma unroll
            for (int n = 0; n < 4; ++n)
                acc[m][n] = __builtin_amdgcn_mfma_f32_16x16x32_bf16(af[m], bfr[n], acc[m][n], 0, 0, 0);
        __syncthreads();
    }

    float local = 0.f;
    #pragma unroll
    for (int m = 0; m < 4; ++m) {
        #pragma unroll
        for (int n = 0; n < 4; ++n) {
            #pragma unroll
            for (int r = 0; r < 4; ++r) {
                int row = wm * 64 + m * 16 + ((lane >> 4) << 2) + r;
                int col = wn * 64 + n * 16 + (lane & 15);
                int gr = ti * BM + row, gc = tj * BM + col;
                float g  = acc[m][n][r];
                float d2 = fmaxf(NA[gr] + NB[gc] - 2.f * g, 0.f);
                float e  = __expf(-d2);
                if (p == 2) {
                    float diff = g - ((gr == gc) ? 1.f : 0.f);
                    local += diff * diff - 2.f * e;
                } else {
                    local += w * e;
                }
            }
        }
    }
    #pragma unroll
    for (int off = 32; off > 0; off >>= 1) local += __shfl_down(local, off);
    if (lane == 0) wsum[wvid] = local;
    __syncthreads();
    if (t == 0) {
        float s = (wsum[0] + wsum[1]) + (wsum[2] + wsum[3]);
        atomicAdd(out, s * (1.f / ((float)NN * (float)NN)));
    }
}

extern "C" void kernel_launch(void* const* d_in, const int* in_sizes, int n_in,
                              void* d_out, int out_size, void* d_ws, size_t ws_size,
                              hipStream_t stream) {
    const float* x = (const float*)d_in[0];
    const float* y = (const float*)d_in[1];
    float* out = (float*)d_out;
    const int nblk = TILES * TILES + 2 * TRI;   // 2080

    hipMemsetAsync(d_out, 0, sizeof(float), stream);

    const size_t need = (size_t)2 * NN * DD * sizeof(ushort) + (size_t)2 * NN * sizeof(float);
    if (ws_size >= need) {
        ushort* bx = (ushort*)d_ws;
        ushort* by = bx + (size_t)NN * DD;
        float*  nx = (float*)(by + (size_t)NN * DD);
        float*  ny = nx + NN;
        prep_kernel<<<dim3(2048), dim3(256), 0, stream>>>(x, y, bx, by, nx, ny);
        fused2_kernel<<<dim3(nblk), dim3(256), 0, stream>>>(bx, by, nx, ny, out);
    } else {
        float* nx = (float*)d_ws;
        float* ny = nx + NN;
        norms_kernel<<<dim3(2048), dim3(256), 0, stream>>>(x, y, nx, ny);
        fused_kernel<<<dim3(nblk), dim3(256), 0, stream>>>(x, y, nx, ny, out);
    }
}